// Round 3
// baseline (908.257 us; speedup 1.0000x reference)
//
#include <hip/hip_runtime.h>
#include <hip/hip_bf16.h>
#include <cstdint>

#define B_IMG   8
#define NCAND   36720
#define PD      85
#define NCLS    80
#define KC      512
#define MAXDET  300
#define NBUCK   2048
#define CANDCAP 2048
#define PPI     12240     // projected pixels per image: 96*96 + 48*48 + 24*24 + 12*12

typedef unsigned int u32;
typedef unsigned long long u64;

__device__ __forceinline__ float leaky(float x){ return x >= 0.f ? x : 0.01f*x; }

__device__ __forceinline__ u64 shfl_u64(u64 v, int lane){
  int lo = __shfl((int)(u32)(v & 0xFFFFFFFFull), lane, 64);
  int hi = __shfl((int)(u32)(v >> 32), lane, 64);
  return ((u64)(u32)hi << 32) | (u64)(u32)lo;
}

// ---------------- K1: score + cls + direct-atomic histogram ----------------
__global__ __launch_bounds__(64) void k_score(const float* __restrict__ preds,
    u32* __restrict__ sbits, int* __restrict__ clsArr, u32* __restrict__ hist){
  __shared__ __align__(16) float tile[64*PD];
  const int img  = blockIdx.y;
  const int lane = threadIdx.x;
  const int base = blockIdx.x * 64;
  const int avail = min(64, NCAND - base);
  const float* src = preds + ((long)img*NCAND + base)*PD;
  if (avail == 64){
    const float4* s4 = (const float4*)src;
    float4* t4 = (float4*)tile;
    #pragma unroll 4
    for (int i = lane; i < (64*PD)/4; i += 64) t4[i] = s4[i];
  } else {
    for (int i = lane; i < avail*PD; i += 64) tile[i] = src[i];
  }
  __syncthreads();
  if (lane < avail){
    const float* p = &tile[lane*PD];
    float obj = p[4];
    float best = p[5]*obj; int bc = 0;      // strict > keeps first max (JAX argmax)
    #pragma unroll 8
    for (int k = 1; k < NCLS; k++){
      float v = p[5+k]*obj;
      if (v > best){ best = v; bc = k; }
    }
    bool valid = (obj > 0.596f) && (best > 0.596f);
    u32 bits = valid ? __float_as_uint(best) : 0u;  // valid scores in (0.596,1)
    long gi = (long)img*NCAND + base + lane;
    sbits[gi]  = bits;
    clsArr[gi] = bc;
    if (bits) atomicAdd(&hist[img*NBUCK + ((bits - 0x3F000000u) >> 12)], 1u);
  }
}

// ---------------- K2: per-image bit-threshold covering top-512 ----------------
__global__ __launch_bounds__(64) void k_thresh(const u32* __restrict__ hist,
                                               u32* __restrict__ thr){
  const int img = blockIdx.x;
  const int lane = threadIdx.x;
  const u32* h = hist + img*NBUCK;
  u32 acc = 0; u32 result = 0x3F000000u; bool found = false;
  for (int g = NBUCK/64 - 1; g >= 0 && !found; g--){
    u32 v = h[g*64 + lane];
    u32 s = v;
    #pragma unroll
    for (int off = 1; off < 64; off <<= 1){
      u32 t = __shfl_down(s, off, 64);
      s += (lane + off < 64) ? t : 0u;
    }
    u64 mask = __ballot(acc + s >= KC);
    if (mask){
      int hl = 63 - __clzll(mask);
      result = 0x3F000000u + ((u32)(g*64 + hl) << 12);
      found = true;
    }
    acc += __shfl(s, 0, 64);
  }
  if (lane == 0) thr[img] = result;
}

// ---------------- K3: gather candidates >= threshold as sortable keys ----------------
__global__ __launch_bounds__(256) void k_gather(const u32* __restrict__ sbits,
    const u32* __restrict__ thr, u32* __restrict__ cnt, u64* __restrict__ cand){
  int img = blockIdx.y;
  int n = blockIdx.x*256 + threadIdx.x;
  if (n >= NCAND) return;
  u32 bits = sbits[(long)img*NCAND + n];
  if (bits && bits >= thr[img]){
    u32 pos = atomicAdd(&cnt[img], 1u);
    if (pos < CANDCAP)
      cand[(long)img*CANDCAP + pos] = ((u64)bits << 32) | (u64)(0xFFFFFFFFu - (u32)n);
  }
}

// ---------------- K4: sort -> exact top-512 -> NMS -> stable top-300 ----------------
__global__ __launch_bounds__(512) void k_nms(const float* __restrict__ preds,
    const int* __restrict__ clsArr, const u64* __restrict__ cand,
    const u32* __restrict__ cnt, float* __restrict__ selbox, u32* __restrict__ selcnt){
#pragma clang fp contract(off)
  __shared__ u64 keys[CANDCAP];
  __shared__ float bx1[KC], by1[KC], bx2[KC], by2[KC];   // class-offset boxes
  __shared__ float ox1[KC], oy1[KC], ox2[KC], oy2[KC];   // original boxes
  __shared__ u64 rows[KC][8];
  __shared__ u64 keepw[8];
  const int img = blockIdx.x;
  const int tid = threadIdx.x;
  const int M = min((int)cnt[img], CANDCAP);
  for (int i = tid; i < CANDCAP; i += 512)
    keys[i] = (i < M) ? cand[(long)img*CANDCAP + i] : 0ull;
  if (tid < 8) keepw[tid] = 0ull;
  __syncthreads();
  // bitonic sort, descending
  for (int k = 2; k <= CANDCAP; k <<= 1){
    for (int j = k >> 1; j > 0; j >>= 1){
      for (int p = tid; p < CANDCAP/2; p += 512){
        int i = ((p & ~(j-1)) << 1) | (p & (j-1));
        int l = i | j;
        u64 a = keys[i], b = keys[l];
        bool desc = ((i & k) == 0);
        if (desc ? (a < b) : (a > b)){ keys[i] = b; keys[l] = a; }
      }
      __syncthreads();
    }
  }
  {
    u64 key = keys[tid];
    bool pos = (key >> 32) != 0ull;
    if (pos){
      u32 idxn = 0xFFFFFFFFu - (u32)(key & 0xFFFFFFFFull);
      const float* p = preds + ((long)img*NCAND + idxn)*PD;
      float cx = p[0], cy = p[1], w = p[2], h = p[3];
      float hw = w*0.5f, hh = h*0.5f;
      float X1 = cx-hw, Y1 = cy-hh, X2 = cx+hw, Y2 = cy+hh;
      float off = (float)clsArr[(long)img*NCAND + idxn] * 4096.0f;
      ox1[tid]=X1; oy1[tid]=Y1; ox2[tid]=X2; oy2[tid]=Y2;
      bx1[tid]=X1+off; by1[tid]=Y1+off; bx2[tid]=X2+off; by2[tid]=Y2+off;
      atomicOr(&keepw[tid>>6], 1ull << (tid & 63));
    } else {
      ox1[tid]=0.f; oy1[tid]=0.f; ox2[tid]=0.f; oy2[tid]=0.f;
      bx1[tid]=-4e8f; by1[tid]=-4e8f; bx2[tid]=-4e8f; by2[tid]=-4e8f;
    }
  }
  __syncthreads();
  {
    const int i = tid;
    float ax1=bx1[i], ay1=by1[i], ax2=bx2[i], ay2=by2[i];
    float areai = (ax2-ax1)*(ay2-ay1);
    for (int w = 0; w < 8; w++){
      u64 bits = 0ull;
      int jbase = w*64;
      for (int b = 0; b < 64; b++){
        int j = jbase + b;
        if (j > i){
          float jx1=bx1[j], jy1=by1[j], jx2=bx2[j], jy2=by2[j];
          float areaj = (jx2-jx1)*(jy2-jy1);
          float ltx = fmaxf(ax1,jx1), lty = fmaxf(ay1,jy1);
          float rbx = fminf(ax2,jx2), rby = fminf(ay2,jy2);
          float ww = fmaxf(rbx-ltx, 0.f);
          float hh = fmaxf(rby-lty, 0.f);
          float inter = ww*hh;
          float iou = inter / (areai + areaj - inter + 1e-7f);
          if (iou > 0.45f) bits |= (1ull << b);
        }
      }
      rows[i][w] = bits;
    }
  }
  __syncthreads();
  if (tid < 64){
    u64 kw = (tid < 8) ? keepw[tid] : 0ull;
    for (int i = 0; i < KC; i++){
      u64 cw = shfl_u64(kw, i >> 6);
      if ((cw >> (i & 63)) & 1ull){
        if (tid < 8) kw &= ~rows[i][tid];
      }
    }
    if (tid < 8) keepw[tid] = kw;
  }
  __syncthreads();
  {
    const int i = tid;
    const int wi = i >> 6, bi = i & 63;
    u64 myw = keepw[wi];
    bool kept = (myw >> bi) & 1ull;
    int rank = 0;
    for (int w = 0; w < wi; w++) rank += __popcll(keepw[w]);
    u64 below = bi ? (myw & ((1ull << bi) - 1ull)) : 0ull;
    rank += __popcll(below);
    if (kept && rank < MAXDET){
      float* sb = selbox + ((long)img*MAXDET + rank)*4;
      sb[0]=ox1[i]; sb[1]=oy1[i]; sb[2]=ox2[i]; sb[3]=oy2[i];
    }
    if (tid == 0){
      int tot = 0;
      for (int w = 0; w < 8; w++) tot += __popcll(keepw[w]);
      selcnt[img] = (u32)min(tot, MAXDET);
    }
  }
}

// ---------------- K5: project feature maps through W1 slice -> G (bf16, HWC) ----------------
// G[img][lvloff+px][j] = sum_c feat[img][c][px] * W1[off+c][j].
// lane = j (W1 row read coalesced, 256B/wave); wave owns 16 contiguous pixels
// (feat read as 4 uniform float4 broadcasts per channel). Each (c,px) element
// is read exactly once. No LDS, no barriers.
__global__ __launch_bounds__(256) void k_proj(const float* __restrict__ feat,
    const float* __restrict__ W1sub, __hip_bfloat16* __restrict__ G,
    int C, int HW, int lvloff){
  const int img  = blockIdx.y;
  const int lane = threadIdx.x & 63;
  const int wave = threadIdx.x >> 6;
  const int p0   = blockIdx.x*64 + wave*16;   // HW % 16 == 0 for all levels
  if (p0 >= HW) return;
  const float* fimg = feat + (long)img*C*HW + p0;
  float acc[16];
  #pragma unroll
  for (int k = 0; k < 16; k++) acc[k] = 0.f;
  #pragma unroll 2
  for (int c = 0; c < C; c++){
    float w = W1sub[(long)c*64 + lane];
    const float4* fp = (const float4*)(fimg + (long)c*HW);
    float4 a0 = fp[0], a1 = fp[1], a2 = fp[2], a3 = fp[3];
    acc[0]+=a0.x*w; acc[1]+=a0.y*w; acc[2]+=a0.z*w; acc[3]+=a0.w*w;
    acc[4]+=a1.x*w; acc[5]+=a1.y*w; acc[6]+=a1.z*w; acc[7]+=a1.w*w;
    acc[8]+=a2.x*w; acc[9]+=a2.y*w; acc[10]+=a2.z*w; acc[11]+=a2.w*w;
    acc[12]+=a3.x*w; acc[13]+=a3.y*w; acc[14]+=a3.z*w; acc[15]+=a3.w*w;
  }
  __hip_bfloat16* g = G + ((long)img*PPI + lvloff + p0)*64 + lane;
  #pragma unroll
  for (int k = 0; k < 16; k++) g[(long)k*64] = __float2bfloat16(acc[k]);
}

// ---------------- K6: fused ROI-gather(on G) + bias + leaky + layer2 + assembly ----------------
__device__ __forceinline__ void roi_level(const __hip_bfloat16* __restrict__ g,
    int Hl, int Wl, float scale, float x1, float y1, float x2, float y2,
    int lane, float& h){
  float bx1=x1*scale, by1=y1*scale, bx2=x2*scale, by2=y2*scale;
  float rw=fmaxf(bx2-bx1,1.f), rh=fmaxf(by2-by1,1.f);
  float ys[2]={by1+rh*0.25f, by1+rh*0.75f};
  float xs[2]={bx1+rw*0.25f, bx1+rw*0.75f};
  #pragma unroll
  for (int pt = 0; pt < 4; pt++){
    float y=ys[pt>>1], x=xs[pt&1];
    if ((y>-1.f)&&(y<(float)Hl)&&(x>-1.f)&&(x<(float)Wl)){   // wave-uniform branch
      float yc=fmaxf(y,0.f), xc=fmaxf(x,0.f);
      int y0=(int)fminf(floorf(yc),(float)(Hl-1));
      int x0=(int)fminf(floorf(xc),(float)(Wl-1));
      int y1i=min(y0+1,Hl-1), x1i=min(x0+1,Wl-1);
      float ly=yc-(float)y0, lx=xc-(float)x0;
      float hy=1.f-ly, hx=1.f-lx;
      h += (hy*hx*0.25f)*__bfloat162float(g[(long)(y0*Wl+x0)*64+lane]);
      h += (hy*lx*0.25f)*__bfloat162float(g[(long)(y0*Wl+x1i)*64+lane]);
      h += (ly*hx*0.25f)*__bfloat162float(g[(long)(y1i*Wl+x0)*64+lane]);
      h += (ly*lx*0.25f)*__bfloat162float(g[(long)(y1i*Wl+x1i)*64+lane]);
    }
  }
}

__global__ __launch_bounds__(256) void k_roi_mlp(const __hip_bfloat16* __restrict__ G,
    const float* __restrict__ selbox, const u32* __restrict__ selcnt,
    const float* __restrict__ b1, const float* __restrict__ W2,
    const float* __restrict__ b2, float* __restrict__ out){
  const int img  = blockIdx.y;
  const int wave = threadIdx.x >> 6;
  const int lane = threadIdx.x & 63;
  const int slot = blockIdx.x*4 + wave;
  if (slot >= MAXDET) return;
  float* o = out + ((long)img*MAXDET + slot)*68;
  if (slot >= (int)selcnt[img]){
    o[4+lane] = 0.f;
    if (lane < 4) o[lane] = 0.f;
    return;
  }
  const float* sb = selbox + ((long)img*MAXDET + slot)*4;
  float x1 = sb[0], y1 = sb[1], x2 = sb[2], y2 = sb[3];
  const __hip_bfloat16* Gi = G + (long)img*PPI*64;
  float h = 0.f;
  roi_level(Gi,             96, 96, 0.125f,    x1,y1,x2,y2, lane, h);
  roi_level(Gi +  9216*64,  48, 48, 0.0625f,   x1,y1,x2,y2, lane, h);
  roi_level(Gi + 11520*64,  24, 24, 0.03125f,  x1,y1,x2,y2, lane, h);
  roi_level(Gi + 12096*64,  12, 12, 0.015625f, x1,y1,x2,y2, lane, h);
  float h1 = leaky(h + b1[lane]);
  float c = 0.f;
  #pragma unroll 8
  for (int k = 0; k < 64; k++){
    float hk = __shfl(h1, k, 64);
    c += hk * W2[k*64 + lane];
  }
  o[4+lane] = leaky(c + b2[lane]);
  if (lane < 4) o[lane] = sb[lane] / 768.0f;
}

// ---------------- workspace layout (bytes) ----------------
// 0        hist   u32[8][2048]        65536
// 65536    cnt    u32[8]              256 (padded)
// 65792    thr    u32[8]              256
// 66048    selbox f32[8][300][4]      38400
// 104448   selcnt u32[8]              256
// 104704   sbits  u32[8][36720]       1175040
// 1279744  cls    i32[8][36720]       1175040
// 2454784  cand   u64[8][2048]        131072
// 2586112  G      bf16[8][12240][64]  12533760   -> total ~15.1 MB

extern "C" void kernel_launch(void* const* d_in, const int* in_sizes, int n_in,
                              void* d_out, int out_size, void* d_ws, size_t ws_size,
                              hipStream_t stream){
  const float* preds = (const float*)d_in[0];
  const float* f1 = (const float*)d_in[1];
  const float* f2 = (const float*)d_in[2];
  const float* f3 = (const float*)d_in[3];
  const float* f4 = (const float*)d_in[4];
  const float* W1 = (const float*)d_in[5];
  const float* b1 = (const float*)d_in[6];
  const float* W2 = (const float*)d_in[7];
  const float* b2 = (const float*)d_in[8];
  float* out = (float*)d_out;
  char* ws = (char*)d_ws;
  u32* hist  = (u32*)(ws + 0);
  u32* cnt   = (u32*)(ws + 65536);
  u32* thr   = (u32*)(ws + 65792);
  float* selb= (float*)(ws + 66048);
  u32* selc  = (u32*)(ws + 104448);
  u32* sbits = (u32*)(ws + 104704);
  int* clsA  = (int*)(ws + 1279744);
  u64* cand  = (u64*)(ws + 2454784);
  __hip_bfloat16* G = (__hip_bfloat16*)(ws + 2586112);

  hipMemsetAsync(ws, 0, 65792, stream);   // zero hist + cnt

  dim3 g1((NCAND+63)/64, B_IMG);
  k_score<<<g1, 64, 0, stream>>>(preds, sbits, clsA, hist);
  k_thresh<<<B_IMG, 64, 0, stream>>>(hist, thr);
  dim3 g3((NCAND+255)/256, B_IMG);
  k_gather<<<g3, 256, 0, stream>>>(sbits, thr, cnt, cand);
  k_nms<<<B_IMG, 512, 0, stream>>>(preds, clsA, cand, cnt, selb, selc);
  // projection: G = feat ^T  W1-slice, per level (independent of NMS result)
  k_proj<<<dim3(144, B_IMG), 256, 0, stream>>>(f1, W1,           G, 128,  96*96, 0);
  k_proj<<<dim3( 36, B_IMG), 256, 0, stream>>>(f2, W1 + 128*64,  G, 256,  48*48, 9216);
  k_proj<<<dim3(  9, B_IMG), 256, 0, stream>>>(f3, W1 + 384*64,  G, 512,  24*24, 11520);
  k_proj<<<dim3(  3, B_IMG), 256, 0, stream>>>(f4, W1 + 896*64,  G, 1024, 12*12, 12096);
  k_roi_mlp<<<dim3((MAXDET+3)/4, B_IMG), 256, 0, stream>>>(G, selb, selc, b1, W2, b2, out);
}

// Round 4
// 621.874 us; speedup vs baseline: 1.4605x; 1.4605x over previous
//
#include <hip/hip_runtime.h>
#include <hip/hip_bf16.h>
#include <cstdint>

#define B_IMG   8
#define NCAND   36720
#define PD      85
#define NCLS    80
#define KC      512
#define MAXDET  300
#define NBUCK   2048
#define CANDCAP 2048
#define PX1     9216      // 96*96 pixels, level 1 (bf16 G1)
#define PXA     3024      // 48*48 + 24*24 + 12*12, levels 2-4 (f32 Gacc)

typedef unsigned int u32;
typedef unsigned long long u64;

__device__ __forceinline__ float leaky(float x){ return x >= 0.f ? x : 0.01f*x; }

__device__ __forceinline__ u64 shfl_u64(u64 v, int lane){
  int lo = __shfl((int)(u32)(v & 0xFFFFFFFFull), lane, 64);
  int hi = __shfl((int)(u32)(v >> 32), lane, 64);
  return ((u64)(u32)hi << 32) | (u64)(u32)lo;
}

// ---------------- K1: score + cls + direct-atomic histogram ----------------
__global__ __launch_bounds__(64) void k_score(const float* __restrict__ preds,
    u32* __restrict__ sbits, int* __restrict__ clsArr, u32* __restrict__ hist){
  __shared__ __align__(16) float tile[64*PD];
  const int img  = blockIdx.y;
  const int lane = threadIdx.x;
  const int base = blockIdx.x * 64;
  const int avail = min(64, NCAND - base);
  const float* src = preds + ((long)img*NCAND + base)*PD;
  if (avail == 64){
    const float4* s4 = (const float4*)src;
    float4* t4 = (float4*)tile;
    #pragma unroll 4
    for (int i = lane; i < (64*PD)/4; i += 64) t4[i] = s4[i];
  } else {
    for (int i = lane; i < avail*PD; i += 64) tile[i] = src[i];
  }
  __syncthreads();
  if (lane < avail){
    const float* p = &tile[lane*PD];
    float obj = p[4];
    float best = p[5]*obj; int bc = 0;      // strict > keeps first max (JAX argmax)
    #pragma unroll 8
    for (int k = 1; k < NCLS; k++){
      float v = p[5+k]*obj;
      if (v > best){ best = v; bc = k; }
    }
    bool valid = (obj > 0.596f) && (best > 0.596f);
    u32 bits = valid ? __float_as_uint(best) : 0u;  // valid scores in (0.596,1)
    long gi = (long)img*NCAND + base + lane;
    sbits[gi]  = bits;
    clsArr[gi] = bc;
    if (bits) atomicAdd(&hist[img*NBUCK + ((bits - 0x3F000000u) >> 12)], 1u);
  }
}

// ---------------- K2: per-image bit-threshold covering top-512 ----------------
__global__ __launch_bounds__(64) void k_thresh(const u32* __restrict__ hist,
                                               u32* __restrict__ thr){
  const int img = blockIdx.x;
  const int lane = threadIdx.x;
  const u32* h = hist + img*NBUCK;
  u32 acc = 0; u32 result = 0x3F000000u; bool found = false;
  for (int g = NBUCK/64 - 1; g >= 0 && !found; g--){
    u32 v = h[g*64 + lane];
    u32 s = v;
    #pragma unroll
    for (int off = 1; off < 64; off <<= 1){
      u32 t = __shfl_down(s, off, 64);
      s += (lane + off < 64) ? t : 0u;
    }
    u64 mask = __ballot(acc + s >= KC);
    if (mask){
      int hl = 63 - __clzll(mask);
      result = 0x3F000000u + ((u32)(g*64 + hl) << 12);
      found = true;
    }
    acc += __shfl(s, 0, 64);
  }
  if (lane == 0) thr[img] = result;
}

// ---------------- K3: gather candidates >= threshold as sortable keys ----------------
__global__ __launch_bounds__(256) void k_gather(const u32* __restrict__ sbits,
    const u32* __restrict__ thr, u32* __restrict__ cnt, u64* __restrict__ cand){
  int img = blockIdx.y;
  int n = blockIdx.x*256 + threadIdx.x;
  if (n >= NCAND) return;
  u32 bits = sbits[(long)img*NCAND + n];
  if (bits && bits >= thr[img]){
    u32 pos = atomicAdd(&cnt[img], 1u);
    if (pos < CANDCAP)
      cand[(long)img*CANDCAP + pos] = ((u64)bits << 32) | (u64)(0xFFFFFFFFu - (u32)n);
  }
}

// ---------------- K4: sort -> exact top-512 -> NMS -> stable top-300 ----------------
__global__ __launch_bounds__(512) void k_nms(const float* __restrict__ preds,
    const int* __restrict__ clsArr, const u64* __restrict__ cand,
    const u32* __restrict__ cnt, float* __restrict__ selbox, u32* __restrict__ selcnt){
#pragma clang fp contract(off)
  __shared__ u64 keys[CANDCAP];
  __shared__ float bx1[KC], by1[KC], bx2[KC], by2[KC];   // class-offset boxes
  __shared__ float ox1[KC], oy1[KC], ox2[KC], oy2[KC];   // original boxes
  __shared__ u64 rows[KC][8];
  __shared__ u64 keepw[8];
  const int img = blockIdx.x;
  const int tid = threadIdx.x;
  const int M = min((int)cnt[img], CANDCAP);
  for (int i = tid; i < CANDCAP; i += 512)
    keys[i] = (i < M) ? cand[(long)img*CANDCAP + i] : 0ull;
  if (tid < 8) keepw[tid] = 0ull;
  __syncthreads();
  // bitonic sort, descending
  for (int k = 2; k <= CANDCAP; k <<= 1){
    for (int j = k >> 1; j > 0; j >>= 1){
      for (int p = tid; p < CANDCAP/2; p += 512){
        int i = ((p & ~(j-1)) << 1) | (p & (j-1));
        int l = i | j;
        u64 a = keys[i], b = keys[l];
        bool desc = ((i & k) == 0);
        if (desc ? (a < b) : (a > b)){ keys[i] = b; keys[l] = a; }
      }
      __syncthreads();
    }
  }
  {
    u64 key = keys[tid];
    bool pos = (key >> 32) != 0ull;
    if (pos){
      u32 idxn = 0xFFFFFFFFu - (u32)(key & 0xFFFFFFFFull);
      const float* p = preds + ((long)img*NCAND + idxn)*PD;
      float cx = p[0], cy = p[1], w = p[2], h = p[3];
      float hw = w*0.5f, hh = h*0.5f;
      float X1 = cx-hw, Y1 = cy-hh, X2 = cx+hw, Y2 = cy+hh;
      float off = (float)clsArr[(long)img*NCAND + idxn] * 4096.0f;
      ox1[tid]=X1; oy1[tid]=Y1; ox2[tid]=X2; oy2[tid]=Y2;
      bx1[tid]=X1+off; by1[tid]=Y1+off; bx2[tid]=X2+off; by2[tid]=Y2+off;
      atomicOr(&keepw[tid>>6], 1ull << (tid & 63));
    } else {
      ox1[tid]=0.f; oy1[tid]=0.f; ox2[tid]=0.f; oy2[tid]=0.f;
      bx1[tid]=-4e8f; by1[tid]=-4e8f; bx2[tid]=-4e8f; by2[tid]=-4e8f;
    }
  }
  __syncthreads();
  {
    const int i = tid;
    float ax1=bx1[i], ay1=by1[i], ax2=bx2[i], ay2=by2[i];
    float areai = (ax2-ax1)*(ay2-ay1);
    for (int w = 0; w < 8; w++){
      u64 bits = 0ull;
      int jbase = w*64;
      for (int b = 0; b < 64; b++){
        int j = jbase + b;
        if (j > i){
          float jx1=bx1[j], jy1=by1[j], jx2=bx2[j], jy2=by2[j];
          float areaj = (jx2-jx1)*(jy2-jy1);
          float ltx = fmaxf(ax1,jx1), lty = fmaxf(ay1,jy1);
          float rbx = fminf(ax2,jx2), rby = fminf(ay2,jy2);
          float ww = fmaxf(rbx-ltx, 0.f);
          float hh = fmaxf(rby-lty, 0.f);
          float inter = ww*hh;
          float iou = inter / (areai + areaj - inter + 1e-7f);
          if (iou > 0.45f) bits |= (1ull << b);
        }
      }
      rows[i][w] = bits;
    }
  }
  __syncthreads();
  if (tid < 64){
    u64 kw = (tid < 8) ? keepw[tid] : 0ull;
    for (int i = 0; i < KC; i++){
      u64 cw = shfl_u64(kw, i >> 6);
      if ((cw >> (i & 63)) & 1ull){
        if (tid < 8) kw &= ~rows[i][tid];
      }
    }
    if (tid < 8) keepw[tid] = kw;
  }
  __syncthreads();
  {
    const int i = tid;
    const int wi = i >> 6, bi = i & 63;
    u64 myw = keepw[wi];
    bool kept = (myw >> bi) & 1ull;
    int rank = 0;
    for (int w = 0; w < wi; w++) rank += __popcll(keepw[w]);
    u64 below = bi ? (myw & ((1ull << bi) - 1ull)) : 0ull;
    rank += __popcll(below);
    if (kept && rank < MAXDET){
      float* sb = selbox + ((long)img*MAXDET + rank)*4;
      sb[0]=ox1[i]; sb[1]=oy1[i]; sb[2]=ox2[i]; sb[3]=oy2[i];
    }
    if (tid == 0){
      int tot = 0;
      for (int w = 0; w < 8; w++) tot += __popcll(keepw[w]);
      selcnt[img] = (u32)min(tot, MAXDET);
    }
  }
}

// ---------------- K5a: level-1 projection, direct bf16 store (C=128, 1 chunk) ----------------
// G1[img][px][j] = sum_c f1[img][c][px] * W1[c][j]. 1152 blocks, 18 waves/CU.
__global__ __launch_bounds__(256) void k_proj_b(const float* __restrict__ feat,
    const float* __restrict__ W1sub, __hip_bfloat16* __restrict__ G1,
    int C, int HW){
  const int img  = blockIdx.y;
  const int lane = threadIdx.x & 63;
  const int wave = threadIdx.x >> 6;
  const int p0   = blockIdx.x*64 + wave*16;
  if (p0 >= HW) return;
  const float* fimg = feat + (long)img*C*HW + p0;
  const float* Wp = W1sub + lane;
  float acc[16];
  #pragma unroll
  for (int k = 0; k < 16; k++) acc[k] = 0.f;
  #pragma unroll 2
  for (int c = 0; c < 128; c++){
    float w = Wp[(long)c*64];
    const float4* fp = (const float4*)(fimg + (long)c*HW);
    float4 a0 = fp[0], a1 = fp[1], a2 = fp[2], a3 = fp[3];
    acc[0]+=a0.x*w; acc[1]+=a0.y*w; acc[2]+=a0.z*w; acc[3]+=a0.w*w;
    acc[4]+=a1.x*w; acc[5]+=a1.y*w; acc[6]+=a1.z*w; acc[7]+=a1.w*w;
    acc[8]+=a2.x*w; acc[9]+=a2.y*w; acc[10]+=a2.z*w; acc[11]+=a2.w*w;
    acc[12]+=a3.x*w; acc[13]+=a3.y*w; acc[14]+=a3.z*w; acc[15]+=a3.w*w;
  }
  __hip_bfloat16* g = G1 + ((long)img*PX1 + p0)*64 + lane;
  #pragma unroll
  for (int k = 0; k < 16; k++) g[(long)k*64] = __float2bfloat16(acc[k]);
}

// ---------------- K5b: levels 2-4 projection, K-split x(C/128), f32 atomic acc ----------------
// grid = (pixel-tiles, C/128, img). Each block: 64 pixels x 128 channels.
// 576+288+192 = 1056 blocks concurrent across the 3 launches (~16 waves/CU)
// vs round-3's 24-block L4 disaster. Atomics: 2/4/8 adders per element,
// wave-coalesced 256B ops.
__global__ __launch_bounds__(256) void k_proj_a(const float* __restrict__ feat,
    const float* __restrict__ W1sub, float* __restrict__ Gacc,
    int C, int HW, int accoff){
  const int img  = blockIdx.z;
  const int c0   = blockIdx.y * 128;
  const int lane = threadIdx.x & 63;
  const int wave = threadIdx.x >> 6;
  const int p0   = blockIdx.x*64 + wave*16;
  if (p0 >= HW) return;
  const float* fimg = feat + ((long)img*C + c0)*HW + p0;
  const float* Wp = W1sub + (long)c0*64 + lane;
  float acc[16];
  #pragma unroll
  for (int k = 0; k < 16; k++) acc[k] = 0.f;
  #pragma unroll 2
  for (int c = 0; c < 128; c++){
    float w = Wp[(long)c*64];
    const float4* fp = (const float4*)(fimg + (long)c*HW);
    float4 a0 = fp[0], a1 = fp[1], a2 = fp[2], a3 = fp[3];
    acc[0]+=a0.x*w; acc[1]+=a0.y*w; acc[2]+=a0.z*w; acc[3]+=a0.w*w;
    acc[4]+=a1.x*w; acc[5]+=a1.y*w; acc[6]+=a1.z*w; acc[7]+=a1.w*w;
    acc[8]+=a2.x*w; acc[9]+=a2.y*w; acc[10]+=a2.z*w; acc[11]+=a2.w*w;
    acc[12]+=a3.x*w; acc[13]+=a3.y*w; acc[14]+=a3.z*w; acc[15]+=a3.w*w;
  }
  float* g = Gacc + ((long)img*PXA + accoff + p0)*64 + lane;
  #pragma unroll
  for (int k = 0; k < 16; k++) atomicAdd(g + (long)k*64, acc[k]);
}

// ---------------- K6: fused ROI-gather + bias + leaky + layer2 + assembly ----------------
template <typename T>
__device__ __forceinline__ float gread(const T* g, long off, int lane);
template <> __device__ __forceinline__ float gread<__hip_bfloat16>(
    const __hip_bfloat16* g, long off, int lane){ return __bfloat162float(g[off*64+lane]); }
template <> __device__ __forceinline__ float gread<float>(
    const float* g, long off, int lane){ return g[off*64+lane]; }

template <typename T>
__device__ __forceinline__ void roi_level(const T* __restrict__ g,
    int Hl, int Wl, float scale, float x1, float y1, float x2, float y2,
    int lane, float& h){
  float bx1=x1*scale, by1=y1*scale, bx2=x2*scale, by2=y2*scale;
  float rw=fmaxf(bx2-bx1,1.f), rh=fmaxf(by2-by1,1.f);
  float ys[2]={by1+rh*0.25f, by1+rh*0.75f};
  float xs[2]={bx1+rw*0.25f, bx1+rw*0.75f};
  #pragma unroll
  for (int pt = 0; pt < 4; pt++){
    float y=ys[pt>>1], x=xs[pt&1];
    if ((y>-1.f)&&(y<(float)Hl)&&(x>-1.f)&&(x<(float)Wl)){   // wave-uniform branch
      float yc=fmaxf(y,0.f), xc=fmaxf(x,0.f);
      int y0=(int)fminf(floorf(yc),(float)(Hl-1));
      int x0=(int)fminf(floorf(xc),(float)(Wl-1));
      int y1i=min(y0+1,Hl-1), x1i=min(x0+1,Wl-1);
      float ly=yc-(float)y0, lx=xc-(float)x0;
      float hy=1.f-ly, hx=1.f-lx;
      h += (hy*hx*0.25f)*gread(g,(long)(y0*Wl+x0),lane);
      h += (hy*lx*0.25f)*gread(g,(long)(y0*Wl+x1i),lane);
      h += (ly*hx*0.25f)*gread(g,(long)(y1i*Wl+x0),lane);
      h += (ly*lx*0.25f)*gread(g,(long)(y1i*Wl+x1i),lane);
    }
  }
}

__global__ __launch_bounds__(256) void k_roi_mlp(const __hip_bfloat16* __restrict__ G1,
    const float* __restrict__ Gacc,
    const float* __restrict__ selbox, const u32* __restrict__ selcnt,
    const float* __restrict__ b1, const float* __restrict__ W2,
    const float* __restrict__ b2, float* __restrict__ out){
  const int img  = blockIdx.y;
  const int wave = threadIdx.x >> 6;
  const int lane = threadIdx.x & 63;
  const int slot = blockIdx.x*4 + wave;
  if (slot >= MAXDET) return;
  float* o = out + ((long)img*MAXDET + slot)*68;
  if (slot >= (int)selcnt[img]){
    o[4+lane] = 0.f;
    if (lane < 4) o[lane] = 0.f;
    return;
  }
  const float* sb = selbox + ((long)img*MAXDET + slot)*4;
  float x1 = sb[0], y1 = sb[1], x2 = sb[2], y2 = sb[3];
  const __hip_bfloat16* G1i = G1 + (long)img*PX1*64;
  const float* Gai = Gacc + (long)img*PXA*64;
  float h = 0.f;
  roi_level(G1i,            96, 96, 0.125f,    x1,y1,x2,y2, lane, h);
  roi_level(Gai,            48, 48, 0.0625f,   x1,y1,x2,y2, lane, h);
  roi_level(Gai + 2304*64,  24, 24, 0.03125f,  x1,y1,x2,y2, lane, h);
  roi_level(Gai + 2880*64,  12, 12, 0.015625f, x1,y1,x2,y2, lane, h);
  float h1 = leaky(h + b1[lane]);
  float c = 0.f;
  #pragma unroll 8
  for (int k = 0; k < 64; k++){
    float hk = __shfl(h1, k, 64);
    c += hk * W2[k*64 + lane];
  }
  o[4+lane] = leaky(c + b2[lane]);
  if (lane < 4) o[lane] = sb[lane] / 768.0f;
}

// ---------------- workspace layout (bytes) ----------------
// 0         hist    u32[8][2048]       65536
// 65536     cnt     u32[8]             256 (padded)
// 65792     thr     u32[8]             256
// 66048     selbox  f32[8][300][4]     38400
// 104448    selcnt  u32[8]             256
// 104704    sbits   u32[8][36720]      1175040
// 1279744   cls     i32[8][36720]      1175040
// 2454784   cand    u64[8][2048]       131072
// 2585856   G1      bf16[8][9216][64]  9437184
// 12023040  Gacc    f32[8][3024][64]   6193152   -> total 18.2 MB

extern "C" void kernel_launch(void* const* d_in, const int* in_sizes, int n_in,
                              void* d_out, int out_size, void* d_ws, size_t ws_size,
                              hipStream_t stream){
  const float* preds = (const float*)d_in[0];
  const float* f1 = (const float*)d_in[1];
  const float* f2 = (const float*)d_in[2];
  const float* f3 = (const float*)d_in[3];
  const float* f4 = (const float*)d_in[4];
  const float* W1 = (const float*)d_in[5];
  const float* b1 = (const float*)d_in[6];
  const float* W2 = (const float*)d_in[7];
  const float* b2 = (const float*)d_in[8];
  float* out = (float*)d_out;
  char* ws = (char*)d_ws;
  u32* hist  = (u32*)(ws + 0);
  u32* cnt   = (u32*)(ws + 65536);
  u32* thr   = (u32*)(ws + 65792);
  float* selb= (float*)(ws + 66048);
  u32* selc  = (u32*)(ws + 104448);
  u32* sbits = (u32*)(ws + 104704);
  int* clsA  = (int*)(ws + 1279744);
  u64* cand  = (u64*)(ws + 2454784);
  __hip_bfloat16* G1 = (__hip_bfloat16*)(ws + 2585856);
  float* Gacc = (float*)(ws + 12023040);

  hipMemsetAsync(ws, 0, 65792, stream);                       // hist + cnt
  hipMemsetAsync(Gacc, 0, (size_t)B_IMG*PXA*64*4, stream);    // K-split accumulator

  dim3 g1((NCAND+63)/64, B_IMG);
  k_score<<<g1, 64, 0, stream>>>(preds, sbits, clsA, hist);
  k_thresh<<<B_IMG, 64, 0, stream>>>(hist, thr);
  dim3 g3((NCAND+255)/256, B_IMG);
  k_gather<<<g3, 256, 0, stream>>>(sbits, thr, cnt, cand);
  k_nms<<<B_IMG, 512, 0, stream>>>(preds, clsA, cand, cnt, selb, selc);
  // projection (independent of NMS result)
  k_proj_b<<<dim3(144, B_IMG),    256, 0, stream>>>(f1, W1,          G1, 128, 96*96);
  k_proj_a<<<dim3(36, 2, B_IMG),  256, 0, stream>>>(f2, W1 + 128*64, Gacc, 256, 48*48, 0);
  k_proj_a<<<dim3(9,  4, B_IMG),  256, 0, stream>>>(f3, W1 + 384*64, Gacc, 512, 24*24, 2304);
  k_proj_a<<<dim3(3,  8, B_IMG),  256, 0, stream>>>(f4, W1 + 896*64, Gacc, 1024, 12*12, 2880);
  k_roi_mlp<<<dim3((MAXDET+3)/4, B_IMG), 256, 0, stream>>>(G1, Gacc, selb, selc, b1, W2, b2, out);
}